// Round 1
// baseline (1081.108 us; speedup 1.0000x reference)
//
#include <hip/hip_runtime.h>
#include <math.h>

// Tree: DEPTH=18, N=2^19-1. Children of i: 2i+1, 2i+2. H=E=64, V=26.
// Level l starts at (1<<l)-1 with B=(1<<l) nodes.
//
// Precomputed folds (exact algebra):
//   (h1,c1)   = lstm_step(lstm_init, 0, 0)           -- same for every node
//   bias2[r]  = (W_hh@h1)[r] + b_ih[r] + b_hh[r]     -- step-2 constant
//   biasS[r]  = b_ih[r] + b_hh[r]                    -- step-3 bias
//   M[j][k]   = (W_tag @ W_comb[:, :64])[j][k]
//   tag_e2[v][j] = b_tag[j] + (W_tag @ (b_comb + W_comb[:,64:] @ emb[v]))[j]
//   node_out(h, v) = log_softmax(M@h + tag_e2[v])
// Memos:
//   memo18[v]            = node_out(h1, v)                      (all leaves)
//   memo17[(l*26+r)*26+v]= node_out(h3(l,r), v)                 (all level-17)

#define OFF_H1C1   0          // 128
#define OFF_BIAS2  128        // 256
#define OFF_BIASS  384        // 256
#define OFF_M      640        // 4096
#define OFF_TAGE2  4736       // 26*64
#define OFF_MEMO18 6400       // 26*64
#define OFF_MEMO17 8064       // 17576*64
#define OFF_BUFA   1132928    // 65536*64
#define OFF_BUFB   5327232    // 32768*64
// total = 7,424,384 floats = ~29.7 MB of d_ws

__device__ __forceinline__ float sigmf(float x){ return 1.0f/(1.0f + expf(-x)); }

__device__ __forceinline__ float rlane(float v, int k){
  // broadcast lane k's value; readlane keeps the LDS pipe free (vs ds_bpermute)
  return __int_as_float(__builtin_amdgcn_readlane(__float_as_int(v), k));
}

__device__ __forceinline__ float logsoftmax64(float tag){
  float m = tag;
  #pragma unroll
  for (int s = 32; s >= 1; s >>= 1) m = fmaxf(m, __shfl_xor(m, s, 64));
  float ex = expf(tag - m);
  float sum = ex;
  #pragma unroll
  for (int s = 32; s >= 1; s >>= 1) sum += __shfl_xor(sum, s, 64);
  return tag - m - logf(sum);
}

// LDS layout for weights: element (row r=g*64+j, col k) of W stored at float
// index (k*64 + ((j+k)&63))*4 + g.  Lane j reads float4 slot k*64+((j+k)&63)
// -> 16B/lane, rotation keeps reads conflict-free; staging writes are ~8-way
// (rare, amortized).  M stored scalar-swizzled: M[j][k] at k*64+((j+k)&63).
__device__ __forceinline__ void stage_wm(const float* __restrict__ W_ih,
                                         const float* __restrict__ W_hh,
                                         const float* __restrict__ Mw,
                                         float* sWih, float* sWhh, float* sMt){
  for (int idx = threadIdx.x; idx < 16384; idx += 256){
    int r = idx >> 6, k = idx & 63;
    int j = r & 63,  g = r >> 6;
    int d = (k*64 + ((j + k) & 63))*4 + g;
    sWih[d] = W_ih[idx];
    sWhh[d] = W_hh[idx];
  }
  for (int idx = threadIdx.x; idx < 4096; idx += 256){
    int jj = idx >> 6, kk = idx & 63;
    sMt[kk*64 + ((jj + kk) & 63)] = Mw[idx];
  }
}

// ---------------- precompute kernel (1 block) ----------------
__global__ __launch_bounds__(256) void k_pre(
    const float* __restrict__ emb,
    const float* __restrict__ W_ih, const float* __restrict__ W_hh,
    const float* __restrict__ b_ih, const float* __restrict__ b_hh,
    const float* __restrict__ W_comb, const float* __restrict__ b_comb,
    const float* __restrict__ W_tag, const float* __restrict__ b_tag,
    const float* __restrict__ lstm_init,
    float* __restrict__ ws)
{
  __shared__ float sWt[4096];    // W_tag
  __shared__ float sWc[8192];    // W_comb
  __shared__ float sg[256];
  __shared__ float sh1[64];
  __shared__ float sceT[64*32];  // comb_e[v][k] at [k*32+v] (transposed, padded)
  __shared__ float sM[4096];
  __shared__ float ste[26*64];   // tag_e2[v][j]
  __shared__ float sth[64];      // (M@h1)[j]
  int t = threadIdx.x;

  for (int idx = t; idx < 4096; idx += 256) sWt[idx] = W_tag[idx];
  for (int idx = t; idx < 8192; idx += 256) sWc[idx] = W_comb[idx];

  float bsum = b_ih[t] + b_hh[t];
  ws[OFF_BIASS + t] = bsum;
  {
    float acc = bsum;
    for (int k = 0; k < 64; k++) acc = fmaf(W_ih[t*64 + k], lstm_init[k], acc);
    sg[t] = acc;
  }
  __syncthreads();

  if (t < 64){
    float ii = sigmf(sg[t]);
    float gg = tanhf(sg[128 + t]);
    float oo = sigmf(sg[192 + t]);
    float c = ii * gg;            // f * 0 + i*g
    float h = oo * tanhf(c);
    sh1[t] = h;
    ws[OFF_H1C1 + t] = h;
    ws[OFF_H1C1 + 64 + t] = c;
  }
  __syncthreads();

  {
    float acc = bsum;
    for (int k = 0; k < 64; k++) acc = fmaf(W_hh[t*64 + k], sh1[k], acc);
    ws[OFF_BIAS2 + t] = acc;
  }
  // comb_e[v][jj] = b_comb[jj] + sum_e W_comb[jj][64+e]*emb[v][e]
  for (int idx = t; idx < 26*64; idx += 256){
    int jj = idx / 26, v = idx - jj*26;
    float acc = b_comb[jj];
    for (int e = 0; e < 64; e++) acc = fmaf(sWc[jj*128 + 64 + e], emb[v*64 + e], acc);
    sceT[jj*32 + v] = acc;
  }
  // M = W_tag @ W_comb[:, :64]
  for (int idx = t; idx < 4096; idx += 256){
    int jj = idx >> 6, kk = idx & 63;
    float acc = 0.f;
    for (int m = 0; m < 64; m++) acc = fmaf(sWt[jj*64 + m], sWc[m*128 + kk], acc);
    sM[idx] = acc;
    ws[OFF_M + idx] = acc;
  }
  __syncthreads();
  // tag_e2[v][jj] = b_tag[jj] + sum_k W_tag[jj][k] * comb_e[v][k]
  for (int idx = t; idx < 26*64; idx += 256){
    int jj = idx / 26, v = idx - jj*26;
    float acc = b_tag[jj];
    for (int k = 0; k < 64; k++) acc = fmaf(sWt[jj*64 + k], sceT[k*32 + v], acc);
    ws[OFF_TAGE2 + v*64 + jj] = acc;
    ste[v*64 + jj] = acc;
  }
  if (t < 64){
    float acc = 0.f;
    for (int k = 0; k < 64; k++) acc = fmaf(sM[t*64 + k], sh1[k], acc);
    sth[t] = acc;
  }
  __syncthreads();
  // memo18[v] = log_softmax(M@h1 + tag_e2[v])
  int w = t >> 6, j = t & 63;
  for (int v = w; v < 26; v += 4){
    float tag = sth[j] + ste[v*64 + j];
    ws[OFF_MEMO18 + v*64 + j] = logsoftmax64(tag);
  }
}

// ---------------- level-17 memo kernel: 676 (lid,rid) pairs ----------------
__global__ __launch_bounds__(256) void k_memo17(const float* __restrict__ W_ih,
                                                const float* __restrict__ W_hh,
                                                float* __restrict__ ws)
{
  __shared__ float4 sWih4[4096];
  __shared__ float4 sWhh4[4096];
  __shared__ float  sMt[4096];
  stage_wm(W_ih, W_hh, ws + OFF_M, (float*)sWih4, (float*)sWhh4, sMt);
  __syncthreads();

  int wv = threadIdx.x >> 6, j = threadIdx.x & 63;
  int p = blockIdx.x*4 + wv;
  if (p >= 676) return;
  int lid = p / 26, rid = p - lid*26;

  const float* memo18 = ws + OFF_MEMO18;
  float L = memo18[lid*64 + j];
  float R = memo18[rid*64 + j];
  float c1 = ws[OFF_H1C1 + 64 + j];

  float a0 = ws[OFF_BIAS2 + j],      a1 = ws[OFF_BIAS2 + 64 + j];
  float a2 = ws[OFF_BIAS2 + 128 + j], a3 = ws[OFF_BIAS2 + 192 + j];
  #pragma unroll 16
  for (int k = 0; k < 64; k++){
    float xk = rlane(L, k);
    float4 w = sWih4[k*64 + ((j + k) & 63)];
    a0 = fmaf(xk, w.x, a0); a1 = fmaf(xk, w.y, a1);
    a2 = fmaf(xk, w.z, a2); a3 = fmaf(xk, w.w, a3);
  }
  float c2 = sigmf(a1)*c1 + sigmf(a0)*tanhf(a2);
  float h2 = sigmf(a3)*tanhf(c2);

  a0 = ws[OFF_BIASS + j];       a1 = ws[OFF_BIASS + 64 + j];
  a2 = ws[OFF_BIASS + 128 + j]; a3 = ws[OFF_BIASS + 192 + j];
  #pragma unroll 16
  for (int k = 0; k < 64; k++){
    float xk = rlane(R, k), hk = rlane(h2, k);
    float4 wi = sWih4[k*64 + ((j + k) & 63)];
    float4 wh = sWhh4[k*64 + ((j + k) & 63)];
    a0 = fmaf(xk, wi.x, fmaf(hk, wh.x, a0));
    a1 = fmaf(xk, wi.y, fmaf(hk, wh.y, a1));
    a2 = fmaf(xk, wi.z, fmaf(hk, wh.z, a2));
    a3 = fmaf(xk, wi.w, fmaf(hk, wh.w, a3));
  }
  float c3 = sigmf(a1)*c2 + sigmf(a0)*tanhf(a2);
  float h3 = sigmf(a3)*tanhf(c3);

  float th = 0.f;
  #pragma unroll 16
  for (int k = 0; k < 64; k++)
    th = fmaf(rlane(h3, k), sMt[k*64 + ((j + k) & 63)], th);

  float* m17 = ws + OFF_MEMO17;
  for (int iid = 0; iid < 26; iid++){
    float tag = th + ws[OFF_TAGE2 + iid*64 + j];
    m17[(p*26 + iid)*64 + j] = logsoftmax64(tag);
  }
}

// ---------------- generic level kernel: 4 nodes per wave ----------------
// mode 0: prev = child rows [2B][64];  mode 1 (level 16): prev = memo17,
// children gathered by ident-key.
__global__ __launch_bounds__(256) void k_level(int B, int mode,
    const int*   __restrict__ ids,
    const float* __restrict__ prev,
    float*       __restrict__ cur,
    const float* __restrict__ W_ih, const float* __restrict__ W_hh,
    float* __restrict__ ws)
{
  __shared__ float4 sWih4[4096];
  __shared__ float4 sWhh4[4096];
  __shared__ float  sMt[4096];
  stage_wm(W_ih, W_hh, ws + OFF_M, (float*)sWih4, (float*)sWhh4, sMt);
  __syncthreads();

  int wv = threadIdx.x >> 6, j = threadIdx.x & 63;
  int i0 = (blockIdx.x*4 + wv)*4;
  if (i0 >= B) return;

  float L[4], R[4];
  #pragma unroll
  for (int t = 0; t < 4; t++){
    int i = i0 + t;
    if (i < B){
      if (mode == 1){
        int m0 = 2*i, m1 = 2*i + 1;
        int kL = (ids[262143 + 2*m0]*26 + ids[262143 + 2*m0 + 1])*26 + ids[131071 + m0];
        int kR = (ids[262143 + 2*m1]*26 + ids[262143 + 2*m1 + 1])*26 + ids[131071 + m1];
        L[t] = prev[kL*64 + j];
        R[t] = prev[kR*64 + j];
      } else {
        L[t] = prev[(2*i)*64 + j];
        R[t] = prev[(2*i + 1)*64 + j];
      }
    } else { L[t] = 0.f; R[t] = 0.f; }
  }

  float c1 = ws[OFF_H1C1 + 64 + j];
  float A0[4], A1[4], A2[4], A3[4];
  {
    float b0 = ws[OFF_BIAS2 + j],      b1 = ws[OFF_BIAS2 + 64 + j];
    float b2 = ws[OFF_BIAS2 + 128 + j], b3 = ws[OFF_BIAS2 + 192 + j];
    #pragma unroll
    for (int t = 0; t < 4; t++){ A0[t]=b0; A1[t]=b1; A2[t]=b2; A3[t]=b3; }
  }
  // step 2: gates = W_ih @ left + (W_hh@h1 + b)
  #pragma unroll 16
  for (int k = 0; k < 64; k++){
    float4 w = sWih4[k*64 + ((j + k) & 63)];
    #pragma unroll
    for (int t = 0; t < 4; t++){
      float xk = rlane(L[t], k);
      A0[t] = fmaf(xk, w.x, A0[t]); A1[t] = fmaf(xk, w.y, A1[t]);
      A2[t] = fmaf(xk, w.z, A2[t]); A3[t] = fmaf(xk, w.w, A3[t]);
    }
  }
  float H2[4], C2[4];
  #pragma unroll
  for (int t = 0; t < 4; t++){
    C2[t] = sigmf(A1[t])*c1 + sigmf(A0[t])*tanhf(A2[t]);
    H2[t] = sigmf(A3[t])*tanhf(C2[t]);
  }
  {
    float b0 = ws[OFF_BIASS + j],      b1 = ws[OFF_BIASS + 64 + j];
    float b2 = ws[OFF_BIASS + 128 + j], b3 = ws[OFF_BIASS + 192 + j];
    #pragma unroll
    for (int t = 0; t < 4; t++){ A0[t]=b0; A1[t]=b1; A2[t]=b2; A3[t]=b3; }
  }
  // step 3: gates = W_ih @ right + W_hh @ h2 + b
  #pragma unroll 16
  for (int k = 0; k < 64; k++){
    float4 wi = sWih4[k*64 + ((j + k) & 63)];
    float4 wh = sWhh4[k*64 + ((j + k) & 63)];
    #pragma unroll
    for (int t = 0; t < 4; t++){
      float xk = rlane(R[t], k), hk = rlane(H2[t], k);
      A0[t] = fmaf(xk, wi.x, fmaf(hk, wh.x, A0[t]));
      A1[t] = fmaf(xk, wi.y, fmaf(hk, wh.y, A1[t]));
      A2[t] = fmaf(xk, wi.z, fmaf(hk, wh.z, A2[t]));
      A3[t] = fmaf(xk, wi.w, fmaf(hk, wh.w, A3[t]));
    }
  }
  float H3[4];
  #pragma unroll
  for (int t = 0; t < 4; t++){
    float c3 = sigmf(A1[t])*C2[t] + sigmf(A0[t])*tanhf(A2[t]);
    H3[t] = sigmf(A3[t])*tanhf(c3);
  }
  // tagh = M @ h3
  float TH[4] = {0.f, 0.f, 0.f, 0.f};
  #pragma unroll 16
  for (int k = 0; k < 64; k++){
    float mt = sMt[k*64 + ((j + k) & 63)];
    #pragma unroll
    for (int t = 0; t < 4; t++) TH[t] = fmaf(rlane(H3[t], k), mt, TH[t]);
  }
  #pragma unroll
  for (int t = 0; t < 4; t++){
    int i = i0 + t;
    if (i < B){
      int id = ids[(B - 1) + i];
      float tag = TH[t] + ws[OFF_TAGE2 + id*64 + j];
      cur[i*64 + j] = logsoftmax64(tag);
    }
  }
}

extern "C" void kernel_launch(void* const* d_in, const int* in_sizes, int n_in,
                              void* d_out, int out_size, void* d_ws, size_t ws_size,
                              hipStream_t stream)
{
  (void)in_sizes; (void)n_in; (void)out_size; (void)ws_size;
  const int*   ids    = (const int*)  d_in[0];
  const float* emb    = (const float*)d_in[1];
  const float* W_ih   = (const float*)d_in[2];
  const float* W_hh   = (const float*)d_in[3];
  const float* b_ih   = (const float*)d_in[4];
  const float* b_hh   = (const float*)d_in[5];
  const float* W_comb = (const float*)d_in[6];
  const float* b_comb = (const float*)d_in[7];
  const float* W_tag  = (const float*)d_in[8];
  const float* b_tag  = (const float*)d_in[9];
  const float* linit  = (const float*)d_in[10];
  float* ws  = (float*)d_ws;
  float* out = (float*)d_out;

  k_pre<<<1, 256, 0, stream>>>(emb, W_ih, W_hh, b_ih, b_hh,
                               W_comb, b_comb, W_tag, b_tag, linit, ws);
  k_memo17<<<169, 256, 0, stream>>>(W_ih, W_hh, ws);

  float* bufA = ws + OFF_BUFA;
  float* bufB = ws + OFF_BUFB;

  // level 16 gathers children via memo17 keys
  k_level<<<4096, 256, 0, stream>>>(65536, 1, ids, ws + OFF_MEMO17, bufA,
                                    W_ih, W_hh, ws);
  const float* prev = bufA;
  for (int l = 15; l >= 1; --l){
    int B = 1 << l;
    float* cur = (l & 1) ? bufB : bufA;
    k_level<<<(B + 15)/16, 256, 0, stream>>>(B, 0, ids, prev, cur,
                                             W_ih, W_hh, ws);
    prev = cur;
  }
  // root: write its 64 log-probs straight to d_out
  k_level<<<1, 256, 0, stream>>>(1, 0, ids, prev, out, W_ih, W_hh, ws);
}

// Round 2
// 962.228 us; speedup vs baseline: 1.1235x; 1.1235x over previous
//
#include <hip/hip_runtime.h>
#include <math.h>

// Tree: DEPTH=18, N=2^19-1. Children of i: 2i+1, 2i+2. H=E=64, V=26.
//
// Exact algebraic folds:
//   (h1,c1)    = lstm_step(lstm_init, 0, 0)          -- same for every node
//   bias2[r]   = (W_hh@h1)[r] + b_ih[r] + b_hh[r]    -- step-2 constant
//   biasS[r]   = b_ih[r] + b_hh[r]                   -- step-3 bias
//   M          = W_tag @ W_comb[:, :64]
//   tag_e2[v]  = b_tag + W_tag@(b_comb + W_comb[:,64:]@emb[v])
//   node_out(h,v) = log_softmax(M@h + tag_e2[v])
// Memos:
//   memo18[v]        = node_out(h1, v)                      (all 2^18 leaves)
//   memo17[key=26^3] = node_out(h3(l,r), v)                 (all 2^17 nodes)
//   h2tab/c2tab[key] = lstm_step(memo17[key], h1, c1)       (level-16 step-2)

#define OFF_H1C1   0          // 128
#define OFF_BIAS2  128        // 256
#define OFF_BIASS  384        // 256
#define OFF_M      640        // 4096
#define OFF_TAGE2  4736       // 26*64
#define OFF_MEMO18 6400       // 26*64
#define OFF_MEMO17 8064       // 17576*64  -> ends 1132928
#define OFF_H2T    1132928    // 17576*64  -> ends 2257792
#define OFF_C2T    2257792    // 17576*64  -> ends 3382656
#define OFF_BUFB   1132928    // 32768*64, aliases H2T/C2T (dead after lvl 16)
#define OFF_BUFA   3382656    // 65536*64  -> ends 7576960 floats (~30.3 MB)

__device__ __forceinline__ float sigmf(float x){
  return __fdividef(1.0f, 1.0f + __expf(-x));      // -x large -> exp=inf -> 0 OK
}
__device__ __forceinline__ float tanhfast(float x){
  float t = __expf(-2.0f * fabsf(x));              // (0,1], underflows to 0
  float r = __fdividef(1.0f - t, 1.0f + t);
  return copysignf(r, x);
}

__device__ __forceinline__ float rlane(float v, int k){
  return __int_as_float(__builtin_amdgcn_readlane(__float_as_int(v), k));
}

__device__ __forceinline__ float logsoftmax64(float tag){
  float m = tag;
  #pragma unroll
  for (int s = 32; s >= 1; s >>= 1) m = fmaxf(m, __shfl_xor(m, s, 64));
  float ex = __expf(tag - m);
  float sum = ex;
  #pragma unroll
  for (int s = 32; s >= 1; s >>= 1) sum += __shfl_xor(sum, s, 64);
  return tag - m - __logf(sum);
}

// LDS weight layout: element (row r=g*64+j, col k) at float index
// (k*64 + ((j+k)&63))*4 + g.  Lane j reads float4 slot k*64+((j+k)&63):
// 16 consecutive lanes hit 256B contiguous -> conflict-free b128.
__device__ __forceinline__ void stage_wm(const float* __restrict__ W_ih,
                                         const float* __restrict__ W_hh,
                                         const float* __restrict__ Mw,
                                         float* sWih, float* sWhh, float* sMt){
  for (int idx = threadIdx.x; idx < 16384; idx += blockDim.x){
    int r = idx >> 6, k = idx & 63;
    int j = r & 63,  g = r >> 6;
    int d = (k*64 + ((j + k) & 63))*4 + g;
    sWih[d] = W_ih[idx];
    sWhh[d] = W_hh[idx];
  }
  for (int idx = threadIdx.x; idx < 4096; idx += blockDim.x){
    int jj = idx >> 6, kk = idx & 63;
    sMt[kk*64 + ((jj + kk) & 63)] = Mw[idx];
  }
}

// ---------------- precompute kernel (1 block) ----------------
__global__ __launch_bounds__(256) void k_pre(
    const float* __restrict__ emb,
    const float* __restrict__ W_ih, const float* __restrict__ W_hh,
    const float* __restrict__ b_ih, const float* __restrict__ b_hh,
    const float* __restrict__ W_comb, const float* __restrict__ b_comb,
    const float* __restrict__ W_tag, const float* __restrict__ b_tag,
    const float* __restrict__ lstm_init,
    float* __restrict__ ws)
{
  __shared__ float sWt[4096];
  __shared__ float sWc[8192];
  __shared__ float sg[256];
  __shared__ float sh1[64];
  __shared__ float sceT[64*32];
  __shared__ float sM[4096];
  __shared__ float ste[26*64];
  __shared__ float sth[64];
  int t = threadIdx.x;

  for (int idx = t; idx < 4096; idx += 256) sWt[idx] = W_tag[idx];
  for (int idx = t; idx < 8192; idx += 256) sWc[idx] = W_comb[idx];

  float bsum = b_ih[t] + b_hh[t];
  ws[OFF_BIASS + t] = bsum;
  {
    float acc = bsum;
    for (int k = 0; k < 64; k++) acc = fmaf(W_ih[t*64 + k], lstm_init[k], acc);
    sg[t] = acc;
  }
  __syncthreads();

  if (t < 64){
    float ii = sigmf(sg[t]);
    float gg = tanhfast(sg[128 + t]);
    float oo = sigmf(sg[192 + t]);
    float c = ii * gg;
    float h = oo * tanhfast(c);
    sh1[t] = h;
    ws[OFF_H1C1 + t] = h;
    ws[OFF_H1C1 + 64 + t] = c;
  }
  __syncthreads();

  {
    float acc = bsum;
    for (int k = 0; k < 64; k++) acc = fmaf(W_hh[t*64 + k], sh1[k], acc);
    ws[OFF_BIAS2 + t] = acc;
  }
  for (int idx = t; idx < 26*64; idx += 256){
    int jj = idx / 26, v = idx - jj*26;
    float acc = b_comb[jj];
    for (int e = 0; e < 64; e++) acc = fmaf(sWc[jj*128 + 64 + e], emb[v*64 + e], acc);
    sceT[jj*32 + v] = acc;
  }
  for (int idx = t; idx < 4096; idx += 256){
    int jj = idx >> 6, kk = idx & 63;
    float acc = 0.f;
    for (int m = 0; m < 64; m++) acc = fmaf(sWt[jj*64 + m], sWc[m*128 + kk], acc);
    sM[idx] = acc;
    ws[OFF_M + idx] = acc;
  }
  __syncthreads();
  for (int idx = t; idx < 26*64; idx += 256){
    int jj = idx / 26, v = idx - jj*26;
    float acc = b_tag[jj];
    for (int k = 0; k < 64; k++) acc = fmaf(sWt[jj*64 + k], sceT[k*32 + v], acc);
    ws[OFF_TAGE2 + v*64 + jj] = acc;
    ste[v*64 + jj] = acc;
  }
  if (t < 64){
    float acc = 0.f;
    for (int k = 0; k < 64; k++) acc = fmaf(sM[t*64 + k], sh1[k], acc);
    sth[t] = acc;
  }
  __syncthreads();
  int w = t >> 6, j = t & 63;
  for (int v = w; v < 26; v += 4){
    float tag = sth[j] + ste[v*64 + j];
    ws[OFF_MEMO18 + v*64 + j] = logsoftmax64(tag);
  }
}

// ---------------- level-17 memo kernel: 676 (lid,rid) pairs ----------------
__global__ __launch_bounds__(256) void k_memo17(const float* __restrict__ W_ih,
                                                const float* __restrict__ W_hh,
                                                float* __restrict__ ws)
{
  __shared__ float4 sWih4[4096];
  __shared__ float4 sWhh4[4096];
  __shared__ float  sMt[4096];
  stage_wm(W_ih, W_hh, ws + OFF_M, (float*)sWih4, (float*)sWhh4, sMt);
  __syncthreads();

  int wv = threadIdx.x >> 6, j = threadIdx.x & 63;
  int p = blockIdx.x*4 + wv;
  if (p >= 676) return;
  int lid = p / 26, rid = p - lid*26;

  const float* memo18 = ws + OFF_MEMO18;
  float L = memo18[lid*64 + j];
  float R = memo18[rid*64 + j];
  float c1 = ws[OFF_H1C1 + 64 + j];

  float a0 = ws[OFF_BIAS2 + j],       a1 = ws[OFF_BIAS2 + 64 + j];
  float a2 = ws[OFF_BIAS2 + 128 + j], a3 = ws[OFF_BIAS2 + 192 + j];
  #pragma unroll 8
  for (int k = 0; k < 64; k++){
    float xk = rlane(L, k);
    float4 w = sWih4[k*64 + ((j + k) & 63)];
    a0 = fmaf(xk, w.x, a0); a1 = fmaf(xk, w.y, a1);
    a2 = fmaf(xk, w.z, a2); a3 = fmaf(xk, w.w, a3);
  }
  float c2 = sigmf(a1)*c1 + sigmf(a0)*tanhfast(a2);
  float h2 = sigmf(a3)*tanhfast(c2);

  a0 = ws[OFF_BIASS + j];       a1 = ws[OFF_BIASS + 64 + j];
  a2 = ws[OFF_BIASS + 128 + j]; a3 = ws[OFF_BIASS + 192 + j];
  #pragma unroll 8
  for (int k = 0; k < 64; k++){
    float xk = rlane(R, k), hk = rlane(h2, k);
    float4 wi = sWih4[k*64 + ((j + k) & 63)];
    float4 wh = sWhh4[k*64 + ((j + k) & 63)];
    a0 = fmaf(xk, wi.x, fmaf(hk, wh.x, a0));
    a1 = fmaf(xk, wi.y, fmaf(hk, wh.y, a1));
    a2 = fmaf(xk, wi.z, fmaf(hk, wh.z, a2));
    a3 = fmaf(xk, wi.w, fmaf(hk, wh.w, a3));
  }
  float c3 = sigmf(a1)*c2 + sigmf(a0)*tanhfast(a2);
  float h3 = sigmf(a3)*tanhfast(c3);

  float th = 0.f;
  #pragma unroll 8
  for (int k = 0; k < 64; k++)
    th = fmaf(rlane(h3, k), sMt[k*64 + ((j + k) & 63)], th);

  float* m17 = ws + OFF_MEMO17;
  for (int iid = 0; iid < 26; iid++){
    float tag = th + ws[OFF_TAGE2 + iid*64 + j];
    m17[(p*26 + iid)*64 + j] = logsoftmax64(tag);
  }
}

// ------- h2/c2 table over 17576 level-17 output keys (level-16 step-2) -------
__global__ __launch_bounds__(512) void k_h2tab(const float* __restrict__ W_ih,
                                               float* __restrict__ ws)
{
  __shared__ float4 sWih4[4096];
  for (int idx = threadIdx.x; idx < 16384; idx += blockDim.x){
    int r = idx >> 6, k = idx & 63;
    int j = r & 63, g = r >> 6;
    ((float*)sWih4)[(k*64 + ((j + k) & 63))*4 + g] = W_ih[idx];
  }
  __syncthreads();

  int wv = threadIdx.x >> 6, j = threadIdx.x & 63;
  int k0 = (blockIdx.x*8 + wv)*8;
  if (k0 >= 17576) return;
  const float* m17 = ws + OFF_MEMO17;
  float c1 = ws[OFF_H1C1 + 64 + j];
  float b0 = ws[OFF_BIAS2 + j],       b1 = ws[OFF_BIAS2 + 64 + j];
  float b2 = ws[OFF_BIAS2 + 128 + j], b3 = ws[OFF_BIAS2 + 192 + j];

  float L[8], A0[8], A1[8], A2[8], A3[8];
  #pragma unroll
  for (int t = 0; t < 8; t++){
    int key = k0 + t;
    L[t] = (key < 17576) ? m17[key*64 + j] : 0.f;
    A0[t] = b0; A1[t] = b1; A2[t] = b2; A3[t] = b3;
  }
  #pragma unroll 4
  for (int k = 0; k < 64; k++){
    float4 w = sWih4[k*64 + ((j + k) & 63)];
    #pragma unroll
    for (int t = 0; t < 8; t++){
      float xk = rlane(L[t], k);
      A0[t] = fmaf(xk, w.x, A0[t]); A1[t] = fmaf(xk, w.y, A1[t]);
      A2[t] = fmaf(xk, w.z, A2[t]); A3[t] = fmaf(xk, w.w, A3[t]);
    }
  }
  #pragma unroll
  for (int t = 0; t < 8; t++){
    int key = k0 + t;
    if (key < 17576){
      float c2 = sigmf(A1[t])*c1 + sigmf(A0[t])*tanhfast(A2[t]);
      float h2 = sigmf(A3[t])*tanhfast(c2);
      ws[OFF_H2T + key*64 + j] = h2;
      ws[OFF_C2T + key*64 + j] = c2;
    }
  }
}

// ---------------- level kernel: 8 waves x 8 nodes, grid-stride ----------------
// MODE 1: level 16 — gather (h2,c2) from h2tab/c2tab and R from memo17 by key.
// MODE 0: generic — children are rows of prev; full step2+step3.
template<int MODE>
__global__ __launch_bounds__(512, 2) void k_level(int B,
    const int*   __restrict__ ids,
    const float* __restrict__ prev,
    float*       __restrict__ cur,
    const float* __restrict__ W_ih, const float* __restrict__ W_hh,
    float* __restrict__ ws)
{
  __shared__ float4 sWih4[4096];
  __shared__ float4 sWhh4[4096];
  __shared__ float  sMt[4096];
  stage_wm(W_ih, W_hh, ws + OFF_M, (float*)sWih4, (float*)sWhh4, sMt);
  __syncthreads();

  int wv = threadIdx.x >> 6, j = threadIdx.x & 63;
  float c1 = ws[OFF_H1C1 + 64 + j];
  float ps0 = ws[OFF_BIASS + j],       ps1 = ws[OFF_BIASS + 64 + j];
  float ps2 = ws[OFF_BIASS + 128 + j], ps3 = ws[OFF_BIASS + 192 + j];
  float p20 = 0.f, p21 = 0.f, p22 = 0.f, p23 = 0.f;
  if (MODE == 0){
    p20 = ws[OFF_BIAS2 + j];       p21 = ws[OFF_BIAS2 + 64 + j];
    p22 = ws[OFF_BIAS2 + 128 + j]; p23 = ws[OFF_BIAS2 + 192 + j];
  }

  for (int i0 = (blockIdx.x*8 + wv)*8; i0 < B; i0 += gridDim.x*64){
    float H2[8], C2[8], R[8];
    float A0[8], A1[8], A2[8], A3[8];

    if (MODE == 1){
      #pragma unroll
      for (int t = 0; t < 8; t++){
        int i = i0 + t;
        if (i < B){
          int m0 = 2*i, m1 = 2*i + 1;
          int kL = (ids[262143 + 2*m0]*26 + ids[262143 + 2*m0 + 1])*26 + ids[131071 + m0];
          int kR = (ids[262143 + 2*m1]*26 + ids[262143 + 2*m1 + 1])*26 + ids[131071 + m1];
          H2[t] = ws[OFF_H2T + kL*64 + j];
          C2[t] = ws[OFF_C2T + kL*64 + j];
          R[t]  = prev[kR*64 + j];
        } else { H2[t] = 0.f; C2[t] = 0.f; R[t] = 0.f; }
      }
    } else {
      float L[8];
      #pragma unroll
      for (int t = 0; t < 8; t++){
        int i = i0 + t;
        if (i < B){
          L[t] = prev[(2*i)*64 + j];
          R[t] = prev[(2*i + 1)*64 + j];
        } else { L[t] = 0.f; R[t] = 0.f; }
        A0[t] = p20; A1[t] = p21; A2[t] = p22; A3[t] = p23;
      }
      #pragma unroll 4
      for (int k = 0; k < 64; k++){
        float4 w = sWih4[k*64 + ((j + k) & 63)];
        #pragma unroll
        for (int t = 0; t < 8; t++){
          float xk = rlane(L[t], k);
          A0[t] = fmaf(xk, w.x, A0[t]); A1[t] = fmaf(xk, w.y, A1[t]);
          A2[t] = fmaf(xk, w.z, A2[t]); A3[t] = fmaf(xk, w.w, A3[t]);
        }
      }
      #pragma unroll
      for (int t = 0; t < 8; t++){
        C2[t] = sigmf(A1[t])*c1 + sigmf(A0[t])*tanhfast(A2[t]);
        H2[t] = sigmf(A3[t])*tanhfast(C2[t]);
      }
    }

    // step 3: gates = W_ih @ R + W_hh @ h2 + biasS
    #pragma unroll
    for (int t = 0; t < 8; t++){ A0[t] = ps0; A1[t] = ps1; A2[t] = ps2; A3[t] = ps3; }
    #pragma unroll 4
    for (int k = 0; k < 64; k++){
      float4 wi = sWih4[k*64 + ((j + k) & 63)];
      float4 wh = sWhh4[k*64 + ((j + k) & 63)];
      #pragma unroll
      for (int t = 0; t < 8; t++){
        float xk = rlane(R[t], k), hk = rlane(H2[t], k);
        A0[t] = fmaf(xk, wi.x, fmaf(hk, wh.x, A0[t]));
        A1[t] = fmaf(xk, wi.y, fmaf(hk, wh.y, A1[t]));
        A2[t] = fmaf(xk, wi.z, fmaf(hk, wh.z, A2[t]));
        A3[t] = fmaf(xk, wi.w, fmaf(hk, wh.w, A3[t]));
      }
    }
    float H3[8];
    #pragma unroll
    for (int t = 0; t < 8; t++){
      float c3 = sigmf(A1[t])*C2[t] + sigmf(A0[t])*tanhfast(A2[t]);
      H3[t] = sigmf(A3[t])*tanhfast(c3);
    }
    // tag = M @ h3
    float TH[8] = {0.f,0.f,0.f,0.f,0.f,0.f,0.f,0.f};
    #pragma unroll 4
    for (int k = 0; k < 64; k++){
      float mt = sMt[k*64 + ((j + k) & 63)];
      #pragma unroll
      for (int t = 0; t < 8; t++) TH[t] = fmaf(rlane(H3[t], k), mt, TH[t]);
    }
    #pragma unroll
    for (int t = 0; t < 8; t++){
      int i = i0 + t;
      if (i < B){
        int id = ids[(B - 1) + i];
        float tag = TH[t] + ws[OFF_TAGE2 + id*64 + j];
        cur[i*64 + j] = logsoftmax64(tag);
      }
    }
  }
}

extern "C" void kernel_launch(void* const* d_in, const int* in_sizes, int n_in,
                              void* d_out, int out_size, void* d_ws, size_t ws_size,
                              hipStream_t stream)
{
  (void)in_sizes; (void)n_in; (void)out_size; (void)ws_size;
  const int*   ids    = (const int*)  d_in[0];
  const float* emb    = (const float*)d_in[1];
  const float* W_ih   = (const float*)d_in[2];
  const float* W_hh   = (const float*)d_in[3];
  const float* b_ih   = (const float*)d_in[4];
  const float* b_hh   = (const float*)d_in[5];
  const float* W_comb = (const float*)d_in[6];
  const float* b_comb = (const float*)d_in[7];
  const float* W_tag  = (const float*)d_in[8];
  const float* b_tag  = (const float*)d_in[9];
  const float* linit  = (const float*)d_in[10];
  float* ws  = (float*)d_ws;
  float* out = (float*)d_out;

  k_pre<<<1, 256, 0, stream>>>(emb, W_ih, W_hh, b_ih, b_hh,
                               W_comb, b_comb, W_tag, b_tag, linit, ws);
  k_memo17<<<169, 256, 0, stream>>>(W_ih, W_hh, ws);
  k_h2tab<<<(17576 + 63)/64, 512, 0, stream>>>(W_ih, ws);

  float* bufA = ws + OFF_BUFA;
  float* bufB = ws + OFF_BUFB;   // aliases h2tab/c2tab — dead after level 16

  // level 16: step-3 only, children via memo17/h2tab keys
  k_level<1><<<256, 512, 0, stream>>>(65536, ids, ws + OFF_MEMO17, bufA,
                                      W_ih, W_hh, ws);
  const float* prev = bufA;
  for (int l = 15; l >= 1; --l){
    int B = 1 << l;
    float* cur = (l & 1) ? bufB : bufA;
    int grid = (B + 63)/64; if (grid > 256) grid = 256;
    k_level<0><<<grid, 512, 0, stream>>>(B, ids, prev, cur, W_ih, W_hh, ws);
    prev = cur;
  }
  k_level<0><<<1, 512, 0, stream>>>(1, ids, prev, out, W_ih, W_hh, ws);
}